// Round 1
// baseline (1844.902 us; speedup 1.0000x reference)
//
#include <hip/hip_runtime.h>
#include <float.h>

#define NN 256
#define KK 20

__global__ __launch_bounds__(256, 2)
void Net_35055523070563_kernel(
    const float* __restrict__ x,
    const float* __restrict__ c1_w0, const float* __restrict__ c1_b0,
    const float* __restrict__ c1_w1, const float* __restrict__ c1_b1,
    const float* __restrict__ c1_w2, const float* __restrict__ c1_b2,
    const float* __restrict__ c2_w0, const float* __restrict__ c2_b0,
    const float* __restrict__ lin1_w, const float* __restrict__ lin1_b,
    const float* __restrict__ m_w0, const float* __restrict__ m_b0,
    const float* __restrict__ m_w1, const float* __restrict__ m_b1,
    const float* __restrict__ m_w2, const float* __restrict__ m_b2,
    float* __restrict__ out)
{
    // Phase-multiplexed region R (36 KB):
    //   P1/P3: knn_d[20*256] @ 0..5119
    //   P2   : s_v[256*20]   @ 0..5119   (stride 20 = bank-spread for b128 gathers)
    //   P2-P3: s_x1[256*16]  @ 5120..9215
    //   P4   : c2t[32*256]   @ 0..8191   (transposed for conflict-free gather)
    //   P5   : shW[48*32]    @ 0..1535
    __shared__ __align__(16) float R[9216];
    __shared__ unsigned char s_ki[KK*NN];          // neighbor idx, lane-minor
    __shared__ __align__(16) float s_xyq[NN*4];    // x0,x1,sq,pad
    __shared__ float s_sq[NN];
    __shared__ float s_w0d[32], s_w0b[32], s_b0[16], s_b1[16], s_b2[16];
    __shared__ __align__(16) float s_W1[256], s_W2[256];
    __shared__ __align__(16) float s_wtd[512], s_wb[512], s_bc[32];
    __shared__ float s_part[128], s_pooled[128], s_head[64];

    float* knn_d = R;
    float* s_v   = R;
    float* s_x1  = R + 5120;
    float* c2t   = R;
    float* shW   = R;

    const int t = threadIdx.x;
    const int b = blockIdx.x;

    // ---------------- stage inputs / weights ----------------
    float2 xv = ((const float2*)x)[b*NN + t];
    float sq0 = xv.x*xv.x + xv.y*xv.y;
    s_xyq[t*4+0] = xv.x; s_xyq[t*4+1] = xv.y; s_xyq[t*4+2] = sq0; s_xyq[t*4+3] = 0.f;
    if (t < 16) { s_b0[t] = c1_b0[t]; s_b1[t] = c1_b1[t]; s_b2[t] = c1_b2[t]; }
    if (t < 32) {
        int r = t >> 4, c = t & 15;
        float wt = c1_w0[r*16+c], wb = c1_w0[(2+r)*16+c];
        s_w0d[t] = wt - wb; s_w0b[t] = wb;
    }
    s_W1[t] = c1_w1[t]; s_W2[t] = c1_w2[t];
    if (t < 32) s_bc[t] = c2_b0[t];
    #pragma unroll
    for (int it = 0; it < 2; ++it) {
        int e = t + it*NN; int k = e >> 5, c = e & 31;
        float wt = c2_w0[k*32+c], wb = c2_w0[(16+k)*32+c];
        s_wtd[e] = wt - wb; s_wb[e] = wb;
    }
    __syncthreads();

    // ---------------- P1: kNN on raw x (d=2) ----------------
    #pragma unroll
    for (int p = 0; p < KK; ++p) knn_d[p*NN + t] = FLT_MAX;
    {
        float worst = FLT_MAX;
        const float xi0 = xv.x, xi1 = xv.y, sqi = sq0;
        for (int j = 0; j < NN; ++j) {
            if (j == t) continue;
            float4 q = ((const float4*)s_xyq)[j];       // uniform -> broadcast
            float dot = xi0*q.x + xi1*q.y;
            float d = (sqi + q.z) - 2.0f*dot;
            if (d < worst) {                            // strict: keeps top_k tie-break
                int p = 19;
                while (p > 0) {
                    float dp = knn_d[(p-1)*NN + t];
                    if (dp <= d) break;
                    knn_d[p*NN + t] = dp;
                    s_ki[p*NN + t]  = s_ki[(p-1)*NN + t];
                    --p;
                }
                knn_d[p*NN + t] = d;
                s_ki[p*NN + t]  = (unsigned char)j;
                worst = knn_d[19*NN + t];
            }
        }
    }
    __syncthreads();

    // ---------------- P2: conv1 (edge MLP 4->16->16->16, max over K) ----------------
    float u[16];
    {
        const float xi0 = xv.x, xi1 = xv.y;
        #pragma unroll
        for (int c = 0; c < 16; ++c) {
            u[c] = s_b0[c] + xi0*s_w0d[c] + xi1*s_w0d[16+c];
            s_v[t*20 + c] = xi0*s_w0b[c] + xi1*s_w0b[16+c];
        }
    }
    __syncthreads();

    float x1f[16];
    {
        float acc[16];
        #pragma unroll
        for (int c = 0; c < 16; ++c) acc[c] = -FLT_MAX;
        #pragma unroll 1
        for (int p = 0; p < KK; p += 2) {
            int j0 = s_ki[p*NN + t], j1 = s_ki[(p+1)*NN + t];
            const float* va = s_v + j0*20;
            const float* vb = s_v + j1*20;
            float h1a[16], h1b[16];
            #pragma unroll
            for (int c = 0; c < 16; ++c) {
                h1a[c] = fmaxf(u[c] + va[c], 0.f);
                h1b[c] = fmaxf(u[c] + vb[c], 0.f);
            }
            float h2a[16], h2b[16];
            #pragma unroll
            for (int c = 0; c < 16; ++c) { h2a[c] = s_b1[c]; h2b[c] = s_b1[c]; }
            #pragma unroll
            for (int k = 0; k < 16; ++k) {
                float fa = h1a[k], fb = h1b[k];
                #pragma unroll
                for (int c = 0; c < 16; ++c) {
                    float w = s_W1[k*16+c];
                    h2a[c] = fmaf(fa, w, h2a[c]);
                    h2b[c] = fmaf(fb, w, h2b[c]);
                }
            }
            #pragma unroll
            for (int c = 0; c < 16; ++c) {
                h2a[c] = fmaxf(h2a[c], 0.f); h2b[c] = fmaxf(h2b[c], 0.f);
                h1a[c] = s_b2[c];            h1b[c] = s_b2[c];   // reuse as h3
            }
            #pragma unroll
            for (int k = 0; k < 16; ++k) {
                float fa = h2a[k], fb = h2b[k];
                #pragma unroll
                for (int c = 0; c < 16; ++c) {
                    float w = s_W2[k*16+c];
                    h1a[c] = fmaf(fa, w, h1a[c]);
                    h1b[c] = fmaf(fb, w, h1b[c]);
                }
            }
            #pragma unroll
            for (int c = 0; c < 16; ++c)
                acc[c] = fmaxf(acc[c], fmaxf(h1a[c], h1b[c]));
        }
        #pragma unroll
        for (int c = 0; c < 16; ++c) { s_x1[t*16 + c] = acc[c]; x1f[c] = acc[c]; }
    }
    float sq2 = 0.f;
    #pragma unroll
    for (int c = 0; c < 16; ++c) sq2 += x1f[c]*x1f[c];
    s_sq[t] = sq2;
    __syncthreads();

    // ---------------- P3: kNN on x1 (d=16) ----------------
    #pragma unroll
    for (int p = 0; p < KK; ++p) knn_d[p*NN + t] = FLT_MAX;
    {
        float worst = FLT_MAX;
        for (int j = 0; j < NN; ++j) {
            if (j == t) continue;
            const float4* xp = (const float4*)(s_x1 + j*16);   // uniform -> broadcast
            float4 q0 = xp[0], q1 = xp[1], q2 = xp[2], q3 = xp[3];
            float dot;
            dot  = x1f[0]*q0.x;  dot += x1f[1]*q0.y;  dot += x1f[2]*q0.z;  dot += x1f[3]*q0.w;
            dot += x1f[4]*q1.x;  dot += x1f[5]*q1.y;  dot += x1f[6]*q1.z;  dot += x1f[7]*q1.w;
            dot += x1f[8]*q2.x;  dot += x1f[9]*q2.y;  dot += x1f[10]*q2.z; dot += x1f[11]*q2.w;
            dot += x1f[12]*q3.x; dot += x1f[13]*q3.y; dot += x1f[14]*q3.z; dot += x1f[15]*q3.w;
            float d = (sq2 + s_sq[j]) - 2.0f*dot;
            if (d < worst) {
                int p = 19;
                while (p > 0) {
                    float dp = knn_d[(p-1)*NN + t];
                    if (dp <= d) break;
                    knn_d[p*NN + t] = dp;
                    s_ki[p*NN + t]  = s_ki[(p-1)*NN + t];
                    --p;
                }
                knn_d[p*NN + t] = d;
                s_ki[p*NN + t]  = (unsigned char)j;
                worst = knn_d[19*NN + t];
            }
        }
    }
    __syncthreads();

    // ---------------- P4: conv2 (affine edge MLP 32->32; max commutes) ----------------
    float x2f[32];
    {
        float cj[32];
        #pragma unroll
        for (int c = 0; c < 32; ++c) cj[c] = 0.f;
        #pragma unroll
        for (int k = 0; k < 16; ++k) {
            float fk = x1f[k];
            #pragma unroll
            for (int c = 0; c < 32; ++c) cj[c] = fmaf(fk, s_wb[k*32+c], cj[c]);
        }
        #pragma unroll
        for (int c = 0; c < 32; ++c) c2t[c*NN + t] = cj[c];    // transposed store
        float ar[32];
        #pragma unroll
        for (int c = 0; c < 32; ++c) ar[c] = s_bc[c];
        #pragma unroll
        for (int k = 0; k < 16; ++k) {
            float fk = x1f[k];
            #pragma unroll
            for (int c = 0; c < 32; ++c) ar[c] = fmaf(fk, s_wtd[k*32+c], ar[c]);
        }
        __syncthreads();
        float mx[32];
        #pragma unroll
        for (int c = 0; c < 32; ++c) mx[c] = -FLT_MAX;
        #pragma unroll 1
        for (int p = 0; p < KK; ++p) {
            int j = s_ki[p*NN + t];
            #pragma unroll
            for (int c = 0; c < 32; ++c) mx[c] = fmaxf(mx[c], c2t[c*NN + j]);
        }
        #pragma unroll
        for (int c = 0; c < 32; ++c) x2f[c] = ar[c] + mx[c];
    }
    __syncthreads();

    // ---------------- P5: lin1 (48->128) + global max pool ----------------
    for (int cc = 0; cc < 4; ++cc) {
        #pragma unroll
        for (int it = 0; it < 6; ++it) {
            int e = t + it*NN; int r = e >> 5, c = e & 31;
            shW[e] = lin1_w[r*128 + cc*32 + c];
        }
        __syncthreads();
        float accL[32];
        #pragma unroll
        for (int c = 0; c < 32; ++c) accL[c] = lin1_b[cc*32 + c];
        #pragma unroll
        for (int k = 0; k < 48; ++k) {
            float fk = (k < 16) ? x1f[k] : x2f[k-16];
            #pragma unroll
            for (int c = 0; c < 32; ++c) accL[c] = fmaf(fk, shW[k*32+c], accL[c]);
        }
        // 64-lane butterfly max, then cross-wave via LDS
        #pragma unroll
        for (int m = 1; m < 64; m <<= 1) {
            #pragma unroll
            for (int c = 0; c < 32; ++c)
                accL[c] = fmaxf(accL[c], __shfl_xor(accL[c], m, 64));
        }
        int w = t >> 6, lane = t & 63;
        if (lane == 0) {
            #pragma unroll
            for (int c = 0; c < 32; ++c) s_part[w*32 + c] = accL[c];
        }
        __syncthreads();
        if (t < 32) {
            float m0 = fmaxf(fmaxf(s_part[t], s_part[32+t]),
                             fmaxf(s_part[64+t], s_part[96+t]));
            s_pooled[cc*32 + t] = m0;
        }
        __syncthreads();
    }

    // ---------------- P6: head MLP 128->64->64->1 ----------------
    if (t < 64) {
        float s = m_b0[t];
        #pragma unroll 8
        for (int k = 0; k < 128; ++k) s = fmaf(s_pooled[k], m_w0[k*64 + t], s);
        s_head[t] = fmaxf(s, 0.f);
    }
    __syncthreads();
    if (t < 64) {
        float s = m_b1[t];
        #pragma unroll 8
        for (int k = 0; k < 64; ++k) s = fmaf(s_head[k], m_w1[k*64 + t], s);
        s = fmaxf(s, 0.f);
        float v = s * m_w2[t];
        #pragma unroll
        for (int m = 1; m < 64; m <<= 1) v += __shfl_xor(v, m, 64);
        if (t == 0) out[b] = v + m_b2[0];
    }
}

extern "C" void kernel_launch(void* const* d_in, const int* in_sizes, int n_in,
                              void* d_out, int out_size, void* d_ws, size_t ws_size,
                              hipStream_t stream) {
    const float* x    = (const float*)d_in[0];
    // d_in[1] = batch (int64) -- unused: batch ids are sorted, N per graph fixed
    const float* c1w0 = (const float*)d_in[2];
    const float* c1b0 = (const float*)d_in[3];
    const float* c1w1 = (const float*)d_in[4];
    const float* c1b1 = (const float*)d_in[5];
    const float* c1w2 = (const float*)d_in[6];
    const float* c1b2 = (const float*)d_in[7];
    const float* c2w0 = (const float*)d_in[8];
    const float* c2b0 = (const float*)d_in[9];
    const float* l1w  = (const float*)d_in[10];
    const float* l1b  = (const float*)d_in[11];
    const float* mw0  = (const float*)d_in[12];
    const float* mb0  = (const float*)d_in[13];
    const float* mw1  = (const float*)d_in[14];
    const float* mb1  = (const float*)d_in[15];
    const float* mw2  = (const float*)d_in[16];
    const float* mb2  = (const float*)d_in[17];
    float* out = (float*)d_out;
    hipLaunchKernelGGL(Net_35055523070563_kernel, dim3(512), dim3(256), 0, stream,
                       x, c1w0, c1b0, c1w1, c1b1, c1w2, c1b2, c2w0, c2b0,
                       l1w, l1b, mw0, mb0, mw1, mb1, mw2, mb2, out);
}

// Round 2
// 814.516 us; speedup vs baseline: 2.2650x; 2.2650x over previous
//
#include <hip/hip_runtime.h>
#include <float.h>

#define NN 256
#define KK 20

__device__ __forceinline__ float med3f(float a, float b, float c) {
    return __builtin_amdgcn_fmed3f(a, b, c);
}

// Distance helpers: called from BOTH pass1 (value top-k) and pass2 (index
// recovery) — identical inlined expression trees guarantee bit-identical d.
__device__ __forceinline__ float dist2d(const float* __restrict__ s_xyq,
                                        float xi0, float xi1, float sqi,
                                        int j, int t) {
    float4 q = ((const float4*)s_xyq)[j];          // uniform -> LDS broadcast
    float dot = xi0*q.x + xi1*q.y;
    float d = (sqi + q.z) - 2.0f*dot;
    return (j == t) ? __builtin_inff() : d;        // self-exclusion, branchless
}

__device__ __forceinline__ float dist16f(const float* __restrict__ s_x1,
                                         const float* __restrict__ s_sq,
                                         const float* __restrict__ x1f,
                                         float sq2, int j, int t) {
    const float4* xp = (const float4*)(s_x1 + (j << 4));   // uniform broadcast
    float4 q0 = xp[0], q1 = xp[1], q2 = xp[2], q3 = xp[3];
    float dot;
    dot  = x1f[0]*q0.x;  dot += x1f[1]*q0.y;  dot += x1f[2]*q0.z;  dot += x1f[3]*q0.w;
    dot += x1f[4]*q1.x;  dot += x1f[5]*q1.y;  dot += x1f[6]*q1.z;  dot += x1f[7]*q1.w;
    dot += x1f[8]*q2.x;  dot += x1f[9]*q2.y;  dot += x1f[10]*q2.z; dot += x1f[11]*q2.w;
    dot += x1f[12]*q3.x; dot += x1f[13]*q3.y; dot += x1f[14]*q3.z; dot += x1f[15]*q3.w;
    float d = (sq2 + s_sq[j]) - 2.0f*dot;
    return (j == t) ? __builtin_inff() : d;
}

__global__ __launch_bounds__(256, 3)
void Net_35055523070563_kernel(
    const float* __restrict__ x,
    const float* __restrict__ c1_w0, const float* __restrict__ c1_b0,
    const float* __restrict__ c1_w1, const float* __restrict__ c1_b1,
    const float* __restrict__ c1_w2, const float* __restrict__ c1_b2,
    const float* __restrict__ c2_w0, const float* __restrict__ c2_b0,
    const float* __restrict__ lin1_w, const float* __restrict__ lin1_b,
    const float* __restrict__ m_w0, const float* __restrict__ m_b0,
    const float* __restrict__ m_w1, const float* __restrict__ m_b1,
    const float* __restrict__ m_w2, const float* __restrict__ m_b2,
    float* __restrict__ out)
{
    // Phase-multiplexed region R (36 KB):
    //   P1 : s_xyq[256*4] @ 0..1023 ; Leq bytes @ floats 1024..1599
    //   P2 : s_v[256*20]  @ 0..5119 ; s_x1[256*16] @ 5120..9215
    //   P3 : s_sq[256] @ 0..255 ; Leq @ 1024..1599 ; s_x1 @ 5120..9215
    //   P4 : c2t[32*256]  @ 0..8191   (transposed for conflict-free gather)
    //   P5 : shW[48*32]   @ 0..1535
    __shared__ __align__(16) float R[9216];
    __shared__ unsigned char s_ki[(KK + 1) * NN];   // 20 rows + trash row, lane-minor
    __shared__ float s_w0d[32], s_w0b[32], s_b0[16], s_b1[16], s_b2[16];
    __shared__ __align__(16) float s_W1[256], s_W2[256];
    __shared__ __align__(16) float s_wtd[512], s_wb[512], s_bc[32];
    __shared__ float s_part[128], s_pooled[128], s_head[64];

    float* s_xyq = R;
    float* s_v   = R;
    float* s_sq  = R;
    float* s_x1  = R + 5120;
    float* c2t   = R;
    float* shW   = R;
    unsigned char* LeqB = (unsigned char*)(R + 1024);   // [9][256] bytes (row 8 = trash)

    const int t = threadIdx.x;
    const int b = blockIdx.x;

    // ---------------- stage inputs / weights ----------------
    float2 xv = ((const float2*)x)[b*NN + t];
    float sq0 = xv.x*xv.x + xv.y*xv.y;
    s_xyq[t*4+0] = xv.x; s_xyq[t*4+1] = xv.y; s_xyq[t*4+2] = sq0; s_xyq[t*4+3] = 0.f;
    if (t < 16) { s_b0[t] = c1_b0[t]; s_b1[t] = c1_b1[t]; s_b2[t] = c1_b2[t]; }
    if (t < 32) {
        int r = t >> 4, c = t & 15;
        float wt = c1_w0[r*16+c], wb = c1_w0[(2+r)*16+c];
        s_w0d[t] = wt - wb; s_w0b[t] = wb;
    }
    s_W1[t] = c1_w1[t]; s_W2[t] = c1_w2[t];
    if (t < 32) s_bc[t] = c2_b0[t];
    #pragma unroll
    for (int it = 0; it < 2; ++it) {
        int e = t + it*NN; int k = e >> 5, c = e & 31;
        float wt = c2_w0[k*32+c], wb = c2_w0[(16+k)*32+c];
        s_wtd[e] = wt - wb; s_wb[e] = wb;
    }
    __syncthreads();

    // ---------------- P1: kNN on raw x (d=2), top-20 in registers ----------------
    {
        float r[KK];
        #pragma unroll
        for (int k = 0; k < KK; ++k) r[k] = __builtin_inff();
        #pragma unroll 4
        for (int j = 0; j < NN; ++j) {
            float d = dist2d(s_xyq, xv.x, xv.y, sq0, j, t);
            #pragma unroll
            for (int k = KK-1; k >= 1; --k) r[k] = med3f(d, r[k-1], r[k]);
            r[0] = fminf(r[0], d);
        }
        // pass 2: recover indices (branchless append; stable tie-break via Leq quota)
        float V = r[KK-1];
        int cntL = 0, cntE = 0;
        #pragma unroll 4
        for (int j = 0; j < NN; ++j) {
            float d = dist2d(s_xyq, xv.x, xv.y, sq0, j, t);
            s_ki[min(cntL, KK)*NN + t] = (unsigned char)j;   // trash row if full
            cntL += (d < V) ? 1 : 0;
            if (d == V) { LeqB[min(cntE, 8)*NN + t] = (unsigned char)j; ++cntE; }
        }
        int need = KK - cntL;                                 // >= 1 always
        for (int e = 0; e < need; ++e)
            s_ki[(cntL + e)*NN + t] = LeqB[e*NN + t];
    }
    __syncthreads();   // all s_xyq reads done before s_v overwrites R[0..]

    // ---------------- P2: conv1 (edge MLP 4->16->16->16, max over K) ----------------
    float u[16];
    {
        #pragma unroll
        for (int c = 0; c < 16; ++c) {
            u[c] = s_b0[c] + xv.x*s_w0d[c] + xv.y*s_w0d[16+c];
            s_v[t*20 + c] = xv.x*s_w0b[c] + xv.y*s_w0b[16+c];
        }
    }
    __syncthreads();

    float x1f[16];
    {
        float acc[16];
        #pragma unroll
        for (int c = 0; c < 16; ++c) acc[c] = -FLT_MAX;
        #pragma unroll 1
        for (int p = 0; p < KK; p += 2) {
            int j0 = s_ki[p*NN + t], j1 = s_ki[(p+1)*NN + t];
            const float* va = s_v + j0*20;
            const float* vb = s_v + j1*20;
            float h1a[16], h1b[16];
            #pragma unroll
            for (int c = 0; c < 16; ++c) {
                h1a[c] = fmaxf(u[c] + va[c], 0.f);
                h1b[c] = fmaxf(u[c] + vb[c], 0.f);
            }
            float h2a[16], h2b[16];
            #pragma unroll
            for (int c = 0; c < 16; ++c) { h2a[c] = s_b1[c]; h2b[c] = s_b1[c]; }
            #pragma unroll
            for (int k = 0; k < 16; ++k) {
                float fa = h1a[k], fb = h1b[k];
                #pragma unroll
                for (int c = 0; c < 16; ++c) {
                    float w = s_W1[k*16+c];
                    h2a[c] = fmaf(fa, w, h2a[c]);
                    h2b[c] = fmaf(fb, w, h2b[c]);
                }
            }
            #pragma unroll
            for (int c = 0; c < 16; ++c) {
                h2a[c] = fmaxf(h2a[c], 0.f); h2b[c] = fmaxf(h2b[c], 0.f);
                h1a[c] = s_b2[c];            h1b[c] = s_b2[c];   // reuse as h3
            }
            #pragma unroll
            for (int k = 0; k < 16; ++k) {
                float fa = h2a[k], fb = h2b[k];
                #pragma unroll
                for (int c = 0; c < 16; ++c) {
                    float w = s_W2[k*16+c];
                    h1a[c] = fmaf(fa, w, h1a[c]);
                    h1b[c] = fmaf(fb, w, h1b[c]);
                }
            }
            #pragma unroll
            for (int c = 0; c < 16; ++c)
                acc[c] = fmaxf(acc[c], fmaxf(h1a[c], h1b[c]));
        }
        #pragma unroll
        for (int c = 0; c < 16; ++c) { s_x1[t*16 + c] = acc[c]; x1f[c] = acc[c]; }
    }
    float sq2 = 0.f;
    #pragma unroll
    for (int c = 0; c < 16; ++c) sq2 += x1f[c]*x1f[c];
    __syncthreads();          // all s_v reads done
    s_sq[t] = sq2;            // s_sq lives at R[0..255] (was s_v)
    __syncthreads();

    // ---------------- P3: kNN on x1 (d=16), top-20 in registers ----------------
    {
        float r[KK];
        #pragma unroll
        for (int k = 0; k < KK; ++k) r[k] = __builtin_inff();
        #pragma unroll 2
        for (int j = 0; j < NN; ++j) {
            float d = dist16f(s_x1, s_sq, x1f, sq2, j, t);
            #pragma unroll
            for (int k = KK-1; k >= 1; --k) r[k] = med3f(d, r[k-1], r[k]);
            r[0] = fminf(r[0], d);
        }
        float V = r[KK-1];
        int cntL = 0, cntE = 0;
        #pragma unroll 2
        for (int j = 0; j < NN; ++j) {
            float d = dist16f(s_x1, s_sq, x1f, sq2, j, t);
            s_ki[min(cntL, KK)*NN + t] = (unsigned char)j;
            cntL += (d < V) ? 1 : 0;
            if (d == V) { LeqB[min(cntE, 8)*NN + t] = (unsigned char)j; ++cntE; }
        }
        int need = KK - cntL;
        for (int e = 0; e < need; ++e)
            s_ki[(cntL + e)*NN + t] = LeqB[e*NN + t];
    }
    __syncthreads();

    // ---------------- P4: conv2 (affine edge MLP 32->32; max commutes) ----------------
    float x2f[32];
    {
        float cj[32];
        #pragma unroll
        for (int c = 0; c < 32; ++c) cj[c] = 0.f;
        #pragma unroll
        for (int k = 0; k < 16; ++k) {
            float fk = x1f[k];
            #pragma unroll
            for (int c = 0; c < 32; ++c) cj[c] = fmaf(fk, s_wb[k*32+c], cj[c]);
        }
        #pragma unroll
        for (int c = 0; c < 32; ++c) c2t[c*NN + t] = cj[c];    // transposed store
        float ar[32];
        #pragma unroll
        for (int c = 0; c < 32; ++c) ar[c] = s_bc[c];
        #pragma unroll
        for (int k = 0; k < 16; ++k) {
            float fk = x1f[k];
            #pragma unroll
            for (int c = 0; c < 32; ++c) ar[c] = fmaf(fk, s_wtd[k*32+c], ar[c]);
        }
        __syncthreads();
        float mx[32];
        #pragma unroll
        for (int c = 0; c < 32; ++c) mx[c] = -FLT_MAX;
        #pragma unroll 1
        for (int p = 0; p < KK; ++p) {
            int j = s_ki[p*NN + t];
            #pragma unroll
            for (int c = 0; c < 32; ++c) mx[c] = fmaxf(mx[c], c2t[c*NN + j]);
        }
        #pragma unroll
        for (int c = 0; c < 32; ++c) x2f[c] = ar[c] + mx[c];
    }
    __syncthreads();

    // ---------------- P5: lin1 (48->128) + global max pool ----------------
    for (int cc = 0; cc < 4; ++cc) {
        #pragma unroll
        for (int it = 0; it < 6; ++it) {
            int e = t + it*NN; int r = e >> 5, c = e & 31;
            shW[e] = lin1_w[r*128 + cc*32 + c];
        }
        __syncthreads();
        float accL[32];
        #pragma unroll
        for (int c = 0; c < 32; ++c) accL[c] = lin1_b[cc*32 + c];
        #pragma unroll
        for (int k = 0; k < 48; ++k) {
            float fk = (k < 16) ? x1f[k] : x2f[k-16];
            #pragma unroll
            for (int c = 0; c < 32; ++c) accL[c] = fmaf(fk, shW[k*32+c], accL[c]);
        }
        #pragma unroll
        for (int m = 1; m < 64; m <<= 1) {
            #pragma unroll
            for (int c = 0; c < 32; ++c)
                accL[c] = fmaxf(accL[c], __shfl_xor(accL[c], m, 64));
        }
        int w = t >> 6, lane = t & 63;
        if (lane == 0) {
            #pragma unroll
            for (int c = 0; c < 32; ++c) s_part[w*32 + c] = accL[c];
        }
        __syncthreads();
        if (t < 32) {
            float m0 = fmaxf(fmaxf(s_part[t], s_part[32+t]),
                             fmaxf(s_part[64+t], s_part[96+t]));
            s_pooled[cc*32 + t] = m0;
        }
        __syncthreads();
    }

    // ---------------- P6: head MLP 128->64->64->1 ----------------
    if (t < 64) {
        float s = m_b0[t];
        #pragma unroll 8
        for (int k = 0; k < 128; ++k) s = fmaf(s_pooled[k], m_w0[k*64 + t], s);
        s_head[t] = fmaxf(s, 0.f);
    }
    __syncthreads();
    if (t < 64) {
        float s = m_b1[t];
        #pragma unroll 8
        for (int k = 0; k < 64; ++k) s = fmaf(s_head[k], m_w1[k*64 + t], s);
        s = fmaxf(s, 0.f);
        float v = s * m_w2[t];
        #pragma unroll
        for (int m = 1; m < 64; m <<= 1) v += __shfl_xor(v, m, 64);
        if (t == 0) out[b] = v + m_b2[0];
    }
}

extern "C" void kernel_launch(void* const* d_in, const int* in_sizes, int n_in,
                              void* d_out, int out_size, void* d_ws, size_t ws_size,
                              hipStream_t stream) {
    const float* x    = (const float*)d_in[0];
    // d_in[1] = batch (int64) -- unused: batch ids are sorted, N per graph fixed
    const float* c1w0 = (const float*)d_in[2];
    const float* c1b0 = (const float*)d_in[3];
    const float* c1w1 = (const float*)d_in[4];
    const float* c1b1 = (const float*)d_in[5];
    const float* c1w2 = (const float*)d_in[6];
    const float* c1b2 = (const float*)d_in[7];
    const float* c2w0 = (const float*)d_in[8];
    const float* c2b0 = (const float*)d_in[9];
    const float* l1w  = (const float*)d_in[10];
    const float* l1b  = (const float*)d_in[11];
    const float* mw0  = (const float*)d_in[12];
    const float* mb0  = (const float*)d_in[13];
    const float* mw1  = (const float*)d_in[14];
    const float* mb1  = (const float*)d_in[15];
    const float* mw2  = (const float*)d_in[16];
    const float* mb2  = (const float*)d_in[17];
    float* out = (float*)d_out;
    hipLaunchKernelGGL(Net_35055523070563_kernel, dim3(512), dim3(256), 0, stream,
                       x, c1w0, c1b0, c1w1, c1b1, c1w2, c1b2, c2w0, c2b0,
                       l1w, l1b, mw0, mb0, mw1, mb1, mw2, mb2, out);
}

// Round 4
// 811.217 us; speedup vs baseline: 2.2742x; 1.0041x over previous
//
#include <hip/hip_runtime.h>
#include <float.h>

#define NN 256
#define KK 20

__device__ __forceinline__ float med3f(float a, float b, float c) {
    return __builtin_amdgcn_fmed3f(a, b, c);
}

// Distance helpers: called from BOTH pass1 (value top-k) and pass2 (index
// recovery) — identical inlined expression trees guarantee bit-identical d.
__device__ __forceinline__ float dist2d(const float* __restrict__ s_xyq,
                                        float xi0, float xi1, float sqi,
                                        int j, int t) {
    float4 q = ((const float4*)s_xyq)[j];          // uniform -> LDS broadcast
    float dot = xi0*q.x + xi1*q.y;
    float d = (sqi + q.z) - 2.0f*dot;
    return (j == t) ? __builtin_inff() : d;        // self-exclusion, branchless
}

__device__ __forceinline__ float dist16f(const float* __restrict__ s_x1,
                                         const float* __restrict__ s_sq,
                                         const float* __restrict__ x1f,
                                         float sq2, int j, int t) {
    const float4* xp = (const float4*)(s_x1 + (j << 4));   // uniform broadcast
    float4 q0 = xp[0], q1 = xp[1], q2 = xp[2], q3 = xp[3];
    float dot;
    dot  = x1f[0]*q0.x;  dot += x1f[1]*q0.y;  dot += x1f[2]*q0.z;  dot += x1f[3]*q0.w;
    dot += x1f[4]*q1.x;  dot += x1f[5]*q1.y;  dot += x1f[6]*q1.z;  dot += x1f[7]*q1.w;
    dot += x1f[8]*q2.x;  dot += x1f[9]*q2.y;  dot += x1f[10]*q2.z; dot += x1f[11]*q2.w;
    dot += x1f[12]*q3.x; dot += x1f[13]*q3.y; dot += x1f[14]*q3.z; dot += x1f[15]*q3.w;
    float d = (sq2 + s_sq[j]) - 2.0f*dot;
    return (j == t) ? __builtin_inff() : d;
}

// waves_per_eu(3,3): LDS (50.7 KB) caps us at 3 blocks/CU = 3 waves/EU anyway.
// Pinning min=max stops the allocator from spilling to chase 4-6 waves/EU
// (round 1: 128 VGPR = 4-wave step; round 2: 84 VGPR = 6-wave step; both
// produced >1 GB of scratch traffic). Cap becomes ~168 VGPR, demand ~125.
__global__ __attribute__((amdgpu_waves_per_eu(3, 3))) __launch_bounds__(256)
void Net_35055523070563_kernel(
    const float* __restrict__ x,
    const float* __restrict__ c1_w0, const float* __restrict__ c1_b0,
    const float* __restrict__ c1_w1, const float* __restrict__ c1_b1,
    const float* __restrict__ c1_w2, const float* __restrict__ c1_b2,
    const float* __restrict__ c2_w0, const float* __restrict__ c2_b0,
    const float* __restrict__ lin1_w, const float* __restrict__ lin1_b,
    const float* __restrict__ m_w0, const float* __restrict__ m_b0,
    const float* __restrict__ m_w1, const float* __restrict__ m_b1,
    const float* __restrict__ m_w2, const float* __restrict__ m_b2,
    float* __restrict__ out)
{
    // Phase-multiplexed region R (36 KB):
    //   P1 : s_xyq[256*4] @ 0..1023 ; Leq bytes @ floats 1024..1599
    //   P2 : s_v[256*20]  @ 0..5119 ; s_x1[256*16] @ 5120..9215
    //   P3 : s_sq[256] @ 0..255 ; Leq @ 1024..1599 ; s_x1 @ 5120..9215
    //   P4 : c2t[32*256]  @ 0..8191   (transposed for conflict-free gather)
    //   P5 : shW[48*32]   @ 0..1535
    __shared__ __align__(16) float R[9216];
    __shared__ unsigned char s_ki[(KK + 1) * NN];   // 20 rows + trash row, lane-minor
    __shared__ float s_w0d[32], s_w0b[32], s_b0[16], s_b1[16], s_b2[16];
    __shared__ __align__(16) float s_W1[256], s_W2[256];
    __shared__ __align__(16) float s_wtd[512], s_wb[512], s_bc[32];
    __shared__ float s_part[128], s_pooled[128], s_head[64];

    float* s_xyq = R;
    float* s_v   = R;
    float* s_sq  = R;
    float* s_x1  = R + 5120;
    float* c2t   = R;
    float* shW   = R;
    unsigned char* LeqB = (unsigned char*)(R + 1024);   // [9][256] bytes (row 8 = trash)

    const int t = threadIdx.x;
    const int b = blockIdx.x;

    // ---------------- stage inputs / weights ----------------
    float2 xv = ((const float2*)x)[b*NN + t];
    float sq0 = xv.x*xv.x + xv.y*xv.y;
    s_xyq[t*4+0] = xv.x; s_xyq[t*4+1] = xv.y; s_xyq[t*4+2] = sq0; s_xyq[t*4+3] = 0.f;
    if (t < 16) { s_b0[t] = c1_b0[t]; s_b1[t] = c1_b1[t]; s_b2[t] = c1_b2[t]; }
    if (t < 32) {
        int r = t >> 4, c = t & 15;
        float wt = c1_w0[r*16+c], wb = c1_w0[(2+r)*16+c];
        s_w0d[t] = wt - wb; s_w0b[t] = wb;
    }
    s_W1[t] = c1_w1[t]; s_W2[t] = c1_w2[t];
    if (t < 32) s_bc[t] = c2_b0[t];
    #pragma unroll
    for (int it = 0; it < 2; ++it) {
        int e = t + it*NN; int k = e >> 5, c = e & 31;
        float wt = c2_w0[k*32+c], wb = c2_w0[(16+k)*32+c];
        s_wtd[e] = wt - wb; s_wb[e] = wb;
    }
    __syncthreads();

    // ---------------- P1: kNN on raw x (d=2), top-20 in registers ----------------
    {
        float r[KK];
        #pragma unroll
        for (int k = 0; k < KK; ++k) r[k] = __builtin_inff();
        #pragma unroll 4
        for (int j = 0; j < NN; ++j) {
            float d = dist2d(s_xyq, xv.x, xv.y, sq0, j, t);
            #pragma unroll
            for (int k = KK-1; k >= 1; --k) r[k] = med3f(d, r[k-1], r[k]);
            r[0] = fminf(r[0], d);
        }
        // pass 2: recover indices (branchless append; stable tie-break via Leq quota)
        float V = r[KK-1];
        int cntL = 0, cntE = 0;
        #pragma unroll 4
        for (int j = 0; j < NN; ++j) {
            float d = dist2d(s_xyq, xv.x, xv.y, sq0, j, t);
            s_ki[min(cntL, KK)*NN + t] = (unsigned char)j;   // trash row if full
            cntL += (d < V) ? 1 : 0;
            if (d == V) { LeqB[min(cntE, 8)*NN + t] = (unsigned char)j; ++cntE; }
        }
        int need = KK - cntL;                                 // >= 1 always
        for (int e = 0; e < need; ++e)
            s_ki[(cntL + e)*NN + t] = LeqB[e*NN + t];
    }
    __syncthreads();   // all s_xyq reads done before s_v overwrites R[0..]

    // ---------------- P2: conv1 (edge MLP 4->16->16->16, max over K) ----------------
    float u[16];
    {
        #pragma unroll
        for (int c = 0; c < 16; ++c) {
            u[c] = s_b0[c] + xv.x*s_w0d[c] + xv.y*s_w0d[16+c];
            s_v[t*20 + c] = xv.x*s_w0b[c] + xv.y*s_w0b[16+c];
        }
    }
    __syncthreads();

    float x1f[16];
    {
        float acc[16];
        #pragma unroll
        for (int c = 0; c < 16; ++c) acc[c] = -FLT_MAX;
        #pragma unroll 1
        for (int p = 0; p < KK; p += 2) {
            int j0 = s_ki[p*NN + t], j1 = s_ki[(p+1)*NN + t];
            const float* va = s_v + j0*20;
            const float* vb = s_v + j1*20;
            float h1a[16], h1b[16];
            #pragma unroll
            for (int c = 0; c < 16; ++c) {
                h1a[c] = fmaxf(u[c] + va[c], 0.f);
                h1b[c] = fmaxf(u[c] + vb[c], 0.f);
            }
            float h2a[16], h2b[16];
            #pragma unroll
            for (int c = 0; c < 16; ++c) { h2a[c] = s_b1[c]; h2b[c] = s_b1[c]; }
            #pragma unroll
            for (int k = 0; k < 16; ++k) {
                float fa = h1a[k], fb = h1b[k];
                #pragma unroll
                for (int c = 0; c < 16; ++c) {
                    float w = s_W1[k*16+c];
                    h2a[c] = fmaf(fa, w, h2a[c]);
                    h2b[c] = fmaf(fb, w, h2b[c]);
                }
            }
            #pragma unroll
            for (int c = 0; c < 16; ++c) {
                h2a[c] = fmaxf(h2a[c], 0.f); h2b[c] = fmaxf(h2b[c], 0.f);
                h1a[c] = s_b2[c];            h1b[c] = s_b2[c];   // reuse as h3
            }
            #pragma unroll
            for (int k = 0; k < 16; ++k) {
                float fa = h2a[k], fb = h2b[k];
                #pragma unroll
                for (int c = 0; c < 16; ++c) {
                    float w = s_W2[k*16+c];
                    h1a[c] = fmaf(fa, w, h1a[c]);
                    h1b[c] = fmaf(fb, w, h1b[c]);
                }
            }
            #pragma unroll
            for (int c = 0; c < 16; ++c)
                acc[c] = fmaxf(acc[c], fmaxf(h1a[c], h1b[c]));
        }
        #pragma unroll
        for (int c = 0; c < 16; ++c) { s_x1[t*16 + c] = acc[c]; x1f[c] = acc[c]; }
    }
    float sq2 = 0.f;
    #pragma unroll
    for (int c = 0; c < 16; ++c) sq2 += x1f[c]*x1f[c];
    __syncthreads();          // all s_v reads done
    s_sq[t] = sq2;            // s_sq lives at R[0..255] (was s_v)
    __syncthreads();

    // ---------------- P3: kNN on x1 (d=16), top-20 in registers ----------------
    {
        float r[KK];
        #pragma unroll
        for (int k = 0; k < KK; ++k) r[k] = __builtin_inff();
        #pragma unroll 2
        for (int j = 0; j < NN; ++j) {
            float d = dist16f(s_x1, s_sq, x1f, sq2, j, t);
            #pragma unroll
            for (int k = KK-1; k >= 1; --k) r[k] = med3f(d, r[k-1], r[k]);
            r[0] = fminf(r[0], d);
        }
        float V = r[KK-1];
        int cntL = 0, cntE = 0;
        #pragma unroll 2
        for (int j = 0; j < NN; ++j) {
            float d = dist16f(s_x1, s_sq, x1f, sq2, j, t);
            s_ki[min(cntL, KK)*NN + t] = (unsigned char)j;
            cntL += (d < V) ? 1 : 0;
            if (d == V) { LeqB[min(cntE, 8)*NN + t] = (unsigned char)j; ++cntE; }
        }
        int need = KK - cntL;
        for (int e = 0; e < need; ++e)
            s_ki[(cntL + e)*NN + t] = LeqB[e*NN + t];
    }
    __syncthreads();

    // ---------------- P4: conv2 (affine edge MLP 32->32; max commutes) ----------------
    float x2f[32];
    {
        float cj[32];
        #pragma unroll
        for (int c = 0; c < 32; ++c) cj[c] = 0.f;
        #pragma unroll
        for (int k = 0; k < 16; ++k) {
            float fk = x1f[k];
            #pragma unroll
            for (int c = 0; c < 32; ++c) cj[c] = fmaf(fk, s_wb[k*32+c], cj[c]);
        }
        #pragma unroll
        for (int c = 0; c < 32; ++c) c2t[c*NN + t] = cj[c];    // transposed store
        float ar[32];
        #pragma unroll
        for (int c = 0; c < 32; ++c) ar[c] = s_bc[c];
        #pragma unroll
        for (int k = 0; k < 16; ++k) {
            float fk = x1f[k];
            #pragma unroll
            for (int c = 0; c < 32; ++c) ar[c] = fmaf(fk, s_wtd[k*32+c], ar[c]);
        }
        __syncthreads();
        float mx[32];
        #pragma unroll
        for (int c = 0; c < 32; ++c) mx[c] = -FLT_MAX;
        #pragma unroll 1
        for (int p = 0; p < KK; ++p) {
            int j = s_ki[p*NN + t];
            #pragma unroll
            for (int c = 0; c < 32; ++c) mx[c] = fmaxf(mx[c], c2t[c*NN + j]);
        }
        #pragma unroll
        for (int c = 0; c < 32; ++c) x2f[c] = ar[c] + mx[c];
    }
    __syncthreads();

    // ---------------- P5: lin1 (48->128) + global max pool ----------------
    for (int cc = 0; cc < 4; ++cc) {
        #pragma unroll
        for (int it = 0; it < 6; ++it) {
            int e = t + it*NN; int r = e >> 5, c = e & 31;
            shW[e] = lin1_w[r*128 + cc*32 + c];
        }
        __syncthreads();
        float accL[32];
        #pragma unroll
        for (int c = 0; c < 32; ++c) accL[c] = lin1_b[cc*32 + c];
        #pragma unroll
        for (int k = 0; k < 48; ++k) {
            float fk = (k < 16) ? x1f[k] : x2f[k-16];
            #pragma unroll
            for (int c = 0; c < 32; ++c) accL[c] = fmaf(fk, shW[k*32+c], accL[c]);
        }
        #pragma unroll
        for (int m = 1; m < 64; m <<= 1) {
            #pragma unroll
            for (int c = 0; c < 32; ++c)
                accL[c] = fmaxf(accL[c], __shfl_xor(accL[c], m, 64));
        }
        int w = t >> 6, lane = t & 63;
        if (lane == 0) {
            #pragma unroll
            for (int c = 0; c < 32; ++c) s_part[w*32 + c] = accL[c];
        }
        __syncthreads();
        if (t < 32) {
            float m0 = fmaxf(fmaxf(s_part[t], s_part[32+t]),
                             fmaxf(s_part[64+t], s_part[96+t]));
            s_pooled[cc*32 + t] = m0;
        }
        __syncthreads();
    }

    // ---------------- P6: head MLP 128->64->64->1 ----------------
    if (t < 64) {
        float s = m_b0[t];
        #pragma unroll 8
        for (int k = 0; k < 128; ++k) s = fmaf(s_pooled[k], m_w0[k*64 + t], s);
        s_head[t] = fmaxf(s, 0.f);
    }
    __syncthreads();
    if (t < 64) {
        float s = m_b1[t];
        #pragma unroll 8
        for (int k = 0; k < 64; ++k) s = fmaf(s_head[k], m_w1[k*64 + t], s);
        s = fmaxf(s, 0.f);
        float v = s * m_w2[t];
        #pragma unroll
        for (int m = 1; m < 64; m <<= 1) v += __shfl_xor(v, m, 64);
        if (t == 0) out[b] = v + m_b2[0];
    }
}

extern "C" void kernel_launch(void* const* d_in, const int* in_sizes, int n_in,
                              void* d_out, int out_size, void* d_ws, size_t ws_size,
                              hipStream_t stream) {
    const float* x    = (const float*)d_in[0];
    // d_in[1] = batch (int64) -- unused: batch ids are sorted, N per graph fixed
    const float* c1w0 = (const float*)d_in[2];
    const float* c1b0 = (const float*)d_in[3];
    const float* c1w1 = (const float*)d_in[4];
    const float* c1b1 = (const float*)d_in[5];
    const float* c1w2 = (const float*)d_in[6];
    const float* c1b2 = (const float*)d_in[7];
    const float* c2w0 = (const float*)d_in[8];
    const float* c2b0 = (const float*)d_in[9];
    const float* l1w  = (const float*)d_in[10];
    const float* l1b  = (const float*)d_in[11];
    const float* mw0  = (const float*)d_in[12];
    const float* mb0  = (const float*)d_in[13];
    const float* mw1  = (const float*)d_in[14];
    const float* mb1  = (const float*)d_in[15];
    const float* mw2  = (const float*)d_in[16];
    const float* mb2  = (const float*)d_in[17];
    float* out = (float*)d_out;
    hipLaunchKernelGGL(Net_35055523070563_kernel, dim3(512), dim3(256), 0, stream,
                       x, c1w0, c1b0, c1w1, c1b1, c1w2, c1b2, c2w0, c2b0,
                       l1w, l1b, mw0, mb0, mw1, mb1, mw2, mb2, out);
}

// Round 7
// 636.669 us; speedup vs baseline: 2.8977x; 1.2742x over previous
//
#include <hip/hip_runtime.h>
#include <float.h>

#define NN 256
#define KK 20

__device__ __forceinline__ float med3f(float a, float b, float c) {
    return __builtin_amdgcn_fmed3f(a, b, c);
}

// Distance helpers: called from BOTH pass1 (value top-k) and pass2 (index
// recovery) — identical inlined expression trees guarantee bit-identical d.
__device__ __forceinline__ float dist2d(const float* __restrict__ s_xyq,
                                        float xi0, float xi1, float sqi,
                                        int j, int t) {
    float4 q = ((const float4*)s_xyq)[j];          // uniform -> LDS broadcast
    float dot = xi0*q.x + xi1*q.y;
    float d = (sqi + q.z) - 2.0f*dot;
    return (j == t) ? __builtin_inff() : d;        // self-exclusion, branchless
}

__device__ __forceinline__ float dist16f(const float* __restrict__ s_x1,
                                         const float* __restrict__ s_sq,
                                         const float* __restrict__ x1f,
                                         float sq2, int j, int t) {
    const float4* xp = (const float4*)(s_x1 + (j << 4));   // uniform broadcast
    float4 q0 = xp[0], q1 = xp[1], q2 = xp[2], q3 = xp[3];
    float dot;
    dot  = x1f[0]*q0.x;  dot += x1f[1]*q0.y;  dot += x1f[2]*q0.z;  dot += x1f[3]*q0.w;
    dot += x1f[4]*q1.x;  dot += x1f[5]*q1.y;  dot += x1f[6]*q1.z;  dot += x1f[7]*q1.w;
    dot += x1f[8]*q2.x;  dot += x1f[9]*q2.y;  dot += x1f[10]*q2.z; dot += x1f[11]*q2.w;
    dot += x1f[12]*q3.x; dot += x1f[13]*q3.y; dot += x1f[14]*q3.z; dot += x1f[15]*q3.w;
    float d = (sq2 + s_sq[j]) - 2.0f*dot;
    return (j == t) ? __builtin_inff() : d;
}

// launch_bounds(256, 1): grid = 512 blocks on 256 CUs = 2 blocks/CU is all the
// residency we can get, so request minimal occupancy to maximize the VGPR cap.
// Observed cap pattern: arg=2 -> 128 VGPR (spills), arg=3 / waves_per_eu(3,3)
// -> 84 VGPR (heavy spills, 1.7 GB scratch traffic). Demand is ~130 live regs
// in conv1's E=2 inner loop; arg=1 should give >=256 cap -> no spills.
__global__ __launch_bounds__(256, 1)
void Net_35055523070563_kernel(
    const float* __restrict__ x,
    const float* __restrict__ c1_w0, const float* __restrict__ c1_b0,
    const float* __restrict__ c1_w1, const float* __restrict__ c1_b1,
    const float* __restrict__ c1_w2, const float* __restrict__ c1_b2,
    const float* __restrict__ c2_w0, const float* __restrict__ c2_b0,
    const float* __restrict__ lin1_w, const float* __restrict__ lin1_b,
    const float* __restrict__ m_w0, const float* __restrict__ m_b0,
    const float* __restrict__ m_w1, const float* __restrict__ m_b1,
    const float* __restrict__ m_w2, const float* __restrict__ m_b2,
    float* __restrict__ out)
{
    // Phase-multiplexed region R (36 KB):
    //   P1 : s_xyq[256*4] @ 0..1023 ; Leq bytes @ floats 1024..1599
    //   P2 : s_v[256*20]  @ 0..5119 ; s_x1[256*16] @ 5120..9215
    //   P3 : s_sq[256] @ 0..255 ; Leq @ 1024..1599 ; s_x1 @ 5120..9215
    //   P4 : c2t[32*256]  @ 0..8191   (transposed for conflict-free gather)
    //   P5 : shW[48*32]   @ 0..1535
    __shared__ __align__(16) float R[9216];
    __shared__ unsigned char s_ki[(KK + 1) * NN];   // 20 rows + trash row, lane-minor
    __shared__ float s_w0d[32], s_w0b[32], s_b0[16], s_b1[16], s_b2[16];
    __shared__ __align__(16) float s_W1[256], s_W2[256];
    __shared__ __align__(16) float s_wtd[512], s_wb[512], s_bc[32];
    __shared__ float s_part[128], s_pooled[128], s_head[64];

    float* s_xyq = R;
    float* s_v   = R;
    float* s_sq  = R;
    float* s_x1  = R + 5120;
    float* c2t   = R;
    float* shW   = R;
    unsigned char* LeqB = (unsigned char*)(R + 1024);   // [9][256] bytes (row 8 = trash)

    const int t = threadIdx.x;
    const int b = blockIdx.x;

    // ---------------- stage inputs / weights ----------------
    float2 xv = ((const float2*)x)[b*NN + t];
    float sq0 = xv.x*xv.x + xv.y*xv.y;
    s_xyq[t*4+0] = xv.x; s_xyq[t*4+1] = xv.y; s_xyq[t*4+2] = sq0; s_xyq[t*4+3] = 0.f;
    if (t < 16) { s_b0[t] = c1_b0[t]; s_b1[t] = c1_b1[t]; s_b2[t] = c1_b2[t]; }
    if (t < 32) {
        int r = t >> 4, c = t & 15;
        float wt = c1_w0[r*16+c], wb = c1_w0[(2+r)*16+c];
        s_w0d[t] = wt - wb; s_w0b[t] = wb;
    }
    s_W1[t] = c1_w1[t]; s_W2[t] = c1_w2[t];
    if (t < 32) s_bc[t] = c2_b0[t];
    #pragma unroll
    for (int it = 0; it < 2; ++it) {
        int e = t + it*NN; int k = e >> 5, c = e & 31;
        float wt = c2_w0[k*32+c], wb = c2_w0[(16+k)*32+c];
        s_wtd[e] = wt - wb; s_wb[e] = wb;
    }
    __syncthreads();

    // ---------------- P1: kNN on raw x (d=2), top-20 in registers ----------------
    {
        float r[KK];
        #pragma unroll
        for (int k = 0; k < KK; ++k) r[k] = __builtin_inff();
        #pragma unroll 4
        for (int j = 0; j < NN; ++j) {
            float d = dist2d(s_xyq, xv.x, xv.y, sq0, j, t);
            #pragma unroll
            for (int k = KK-1; k >= 1; --k) r[k] = med3f(d, r[k-1], r[k]);
            r[0] = fminf(r[0], d);
        }
        // pass 2: recover indices (branchless append; stable tie-break via Leq quota)
        float V = r[KK-1];
        int cntL = 0, cntE = 0;
        #pragma unroll 4
        for (int j = 0; j < NN; ++j) {
            float d = dist2d(s_xyq, xv.x, xv.y, sq0, j, t);
            s_ki[min(cntL, KK)*NN + t] = (unsigned char)j;   // trash row if full
            cntL += (d < V) ? 1 : 0;
            if (d == V) { LeqB[min(cntE, 8)*NN + t] = (unsigned char)j; ++cntE; }
        }
        int need = KK - cntL;                                 // >= 1 always
        for (int e = 0; e < need; ++e)
            s_ki[(cntL + e)*NN + t] = LeqB[e*NN + t];
    }
    __syncthreads();   // all s_xyq reads done before s_v overwrites R[0..]

    // ---------------- P2: conv1 (edge MLP 4->16->16->16, max over K) ----------------
    float u[16];
    {
        #pragma unroll
        for (int c = 0; c < 16; ++c) {
            u[c] = s_b0[c] + xv.x*s_w0d[c] + xv.y*s_w0d[16+c];
            s_v[t*20 + c] = xv.x*s_w0b[c] + xv.y*s_w0b[16+c];
        }
    }
    __syncthreads();

    float x1f[16];
    {
        float acc[16];
        #pragma unroll
        for (int c = 0; c < 16; ++c) acc[c] = -FLT_MAX;
        #pragma unroll 1
        for (int p = 0; p < KK; p += 2) {
            int j0 = s_ki[p*NN + t], j1 = s_ki[(p+1)*NN + t];
            const float* va = s_v + j0*20;
            const float* vb = s_v + j1*20;
            float h1a[16], h1b[16];
            #pragma unroll
            for (int c = 0; c < 16; ++c) {
                h1a[c] = fmaxf(u[c] + va[c], 0.f);
                h1b[c] = fmaxf(u[c] + vb[c], 0.f);
            }
            float h2a[16], h2b[16];
            #pragma unroll
            for (int c = 0; c < 16; ++c) { h2a[c] = s_b1[c]; h2b[c] = s_b1[c]; }
            #pragma unroll
            for (int k = 0; k < 16; ++k) {
                float fa = h1a[k], fb = h1b[k];
                #pragma unroll
                for (int c = 0; c < 16; ++c) {
                    float w = s_W1[k*16+c];
                    h2a[c] = fmaf(fa, w, h2a[c]);
                    h2b[c] = fmaf(fb, w, h2b[c]);
                }
            }
            #pragma unroll
            for (int c = 0; c < 16; ++c) {
                h2a[c] = fmaxf(h2a[c], 0.f); h2b[c] = fmaxf(h2b[c], 0.f);
                h1a[c] = s_b2[c];            h1b[c] = s_b2[c];   // reuse as h3
            }
            #pragma unroll
            for (int k = 0; k < 16; ++k) {
                float fa = h2a[k], fb = h2b[k];
                #pragma unroll
                for (int c = 0; c < 16; ++c) {
                    float w = s_W2[k*16+c];
                    h1a[c] = fmaf(fa, w, h1a[c]);
                    h1b[c] = fmaf(fb, w, h1b[c]);
                }
            }
            #pragma unroll
            for (int c = 0; c < 16; ++c)
                acc[c] = fmaxf(acc[c], fmaxf(h1a[c], h1b[c]));
        }
        #pragma unroll
        for (int c = 0; c < 16; ++c) { s_x1[t*16 + c] = acc[c]; x1f[c] = acc[c]; }
    }
    float sq2 = 0.f;
    #pragma unroll
    for (int c = 0; c < 16; ++c) sq2 += x1f[c]*x1f[c];
    __syncthreads();          // all s_v reads done
    s_sq[t] = sq2;            // s_sq lives at R[0..255] (was s_v)
    __syncthreads();

    // ---------------- P3: kNN on x1 (d=16), top-20 in registers ----------------
    {
        float r[KK];
        #pragma unroll
        for (int k = 0; k < KK; ++k) r[k] = __builtin_inff();
        #pragma unroll 2
        for (int j = 0; j < NN; ++j) {
            float d = dist16f(s_x1, s_sq, x1f, sq2, j, t);
            #pragma unroll
            for (int k = KK-1; k >= 1; --k) r[k] = med3f(d, r[k-1], r[k]);
            r[0] = fminf(r[0], d);
        }
        float V = r[KK-1];
        int cntL = 0, cntE = 0;
        #pragma unroll 2
        for (int j = 0; j < NN; ++j) {
            float d = dist16f(s_x1, s_sq, x1f, sq2, j, t);
            s_ki[min(cntL, KK)*NN + t] = (unsigned char)j;
            cntL += (d < V) ? 1 : 0;
            if (d == V) { LeqB[min(cntE, 8)*NN + t] = (unsigned char)j; ++cntE; }
        }
        int need = KK - cntL;
        for (int e = 0; e < need; ++e)
            s_ki[(cntL + e)*NN + t] = LeqB[e*NN + t];
    }
    __syncthreads();

    // ---------------- P4: conv2 (affine edge MLP 32->32; max commutes) ----------------
    float x2f[32];
    {
        float cj[32];
        #pragma unroll
        for (int c = 0; c < 32; ++c) cj[c] = 0.f;
        #pragma unroll
        for (int k = 0; k < 16; ++k) {
            float fk = x1f[k];
            #pragma unroll
            for (int c = 0; c < 32; ++c) cj[c] = fmaf(fk, s_wb[k*32+c], cj[c]);
        }
        #pragma unroll
        for (int c = 0; c < 32; ++c) c2t[c*NN + t] = cj[c];    // transposed store
        float ar[32];
        #pragma unroll
        for (int c = 0; c < 32; ++c) ar[c] = s_bc[c];
        #pragma unroll
        for (int k = 0; k < 16; ++k) {
            float fk = x1f[k];
            #pragma unroll
            for (int c = 0; c < 32; ++c) ar[c] = fmaf(fk, s_wtd[k*32+c], ar[c]);
        }
        __syncthreads();
        float mx[32];
        #pragma unroll
        for (int c = 0; c < 32; ++c) mx[c] = -FLT_MAX;
        #pragma unroll 1
        for (int p = 0; p < KK; ++p) {
            int j = s_ki[p*NN + t];
            #pragma unroll
            for (int c = 0; c < 32; ++c) mx[c] = fmaxf(mx[c], c2t[c*NN + j]);
        }
        #pragma unroll
        for (int c = 0; c < 32; ++c) x2f[c] = ar[c] + mx[c];
    }
    __syncthreads();

    // ---------------- P5: lin1 (48->128) + global max pool ----------------
    for (int cc = 0; cc < 4; ++cc) {
        #pragma unroll
        for (int it = 0; it < 6; ++it) {
            int e = t + it*NN; int r = e >> 5, c = e & 31;
            shW[e] = lin1_w[r*128 + cc*32 + c];
        }
        __syncthreads();
        float accL[32];
        #pragma unroll
        for (int c = 0; c < 32; ++c) accL[c] = lin1_b[cc*32 + c];
        #pragma unroll
        for (int k = 0; k < 48; ++k) {
            float fk = (k < 16) ? x1f[k] : x2f[k-16];
            #pragma unroll
            for (int c = 0; c < 32; ++c) accL[c] = fmaf(fk, shW[k*32+c], accL[c]);
        }
        #pragma unroll
        for (int m = 1; m < 64; m <<= 1) {
            #pragma unroll
            for (int c = 0; c < 32; ++c)
                accL[c] = fmaxf(accL[c], __shfl_xor(accL[c], m, 64));
        }
        int w = t >> 6, lane = t & 63;
        if (lane == 0) {
            #pragma unroll
            for (int c = 0; c < 32; ++c) s_part[w*32 + c] = accL[c];
        }
        __syncthreads();
        if (t < 32) {
            float m0 = fmaxf(fmaxf(s_part[t], s_part[32+t]),
                             fmaxf(s_part[64+t], s_part[96+t]));
            s_pooled[cc*32 + t] = m0;
        }
        __syncthreads();
    }

    // ---------------- P6: head MLP 128->64->64->1 ----------------
    if (t < 64) {
        float s = m_b0[t];
        #pragma unroll 8
        for (int k = 0; k < 128; ++k) s = fmaf(s_pooled[k], m_w0[k*64 + t], s);
        s_head[t] = fmaxf(s, 0.f);
    }
    __syncthreads();
    if (t < 64) {
        float s = m_b1[t];
        #pragma unroll 8
        for (int k = 0; k < 64; ++k) s = fmaf(s_head[k], m_w1[k*64 + t], s);
        s = fmaxf(s, 0.f);
        float v = s * m_w2[t];
        #pragma unroll
        for (int m = 1; m < 64; m <<= 1) v += __shfl_xor(v, m, 64);
        if (t == 0) out[b] = v + m_b2[0];
    }
}

extern "C" void kernel_launch(void* const* d_in, const int* in_sizes, int n_in,
                              void* d_out, int out_size, void* d_ws, size_t ws_size,
                              hipStream_t stream) {
    const float* x    = (const float*)d_in[0];
    // d_in[1] = batch (int64) -- unused: batch ids are sorted, N per graph fixed
    const float* c1w0 = (const float*)d_in[2];
    const float* c1b0 = (const float*)d_in[3];
    const float* c1w1 = (const float*)d_in[4];
    const float* c1b1 = (const float*)d_in[5];
    const float* c1w2 = (const float*)d_in[6];
    const float* c1b2 = (const float*)d_in[7];
    const float* c2w0 = (const float*)d_in[8];
    const float* c2b0 = (const float*)d_in[9];
    const float* l1w  = (const float*)d_in[10];
    const float* l1b  = (const float*)d_in[11];
    const float* mw0  = (const float*)d_in[12];
    const float* mb0  = (const float*)d_in[13];
    const float* mw1  = (const float*)d_in[14];
    const float* mb1  = (const float*)d_in[15];
    const float* mw2  = (const float*)d_in[16];
    const float* mb2  = (const float*)d_in[17];
    float* out = (float*)d_out;
    hipLaunchKernelGGL(Net_35055523070563_kernel, dim3(512), dim3(256), 0, stream,
                       x, c1w0, c1b0, c1w1, c1b1, c1w2, c1b2, c2w0, c2b0,
                       l1w, l1b, mw0, mb0, mw1, mb1, mw2, mb2, out);
}